// Round 1
// baseline (180.882 us; speedup 1.0000x reference)
//
#include <hip/hip_runtime.h>
#include <hip/hip_bf16.h>

#define L_SEQ 65536
#define TILE_OUT 62
#define TILES_PER_B 1058   // ceil(65536 / 62)

typedef __attribute__((ext_vector_type(8))) short bf16x8;
typedef __attribute__((ext_vector_type(4))) short s16x4;
typedef __attribute__((ext_vector_type(4))) float f32x4;

// workspace layout (bytes)
#define WS_W1T   0        // bf16 [128][64]  : W1T[j][c] = (W_in@W_ip)^T
#define WS_W2T   16384    // bf16 [64][64]   : W2T[c'][d] = (W_op@W_out)^T
#define WS_WG2T  24576    // bf16 [64][16]   : Wg2T[c][j] = W_g2[j][c]
#define WS_B1    26624    // f32 [128]
#define WS_B2    27136    // f32 [64]
#define WS_CW    27392    // f32 cw0[64] cw1[64] cw2[64] cb[64]

__device__ __forceinline__ short f2bf(float f) {
    union { float f; unsigned u; } a; a.f = f;
    unsigned r = (a.u + 0x7FFFu + ((a.u >> 16) & 1u)) >> 16;  // RNE
    return (short)r;
}
__device__ __forceinline__ float bf2f(short s) {
    union { unsigned u; float f; } a; a.u = ((unsigned)(unsigned short)s) << 16;
    return a.f;
}
__device__ __forceinline__ float fsigmoid(float x) { return 1.0f / (1.0f + __expf(-x)); }
__device__ __forceinline__ float fsilu(float x)    { return x / (1.0f + __expf(-x)); }

__device__ __forceinline__ void ld8(const float* __restrict__ p, float* v) {
    float4 a = *(const float4*)p;
    float4 b = *(const float4*)(p + 4);
    v[0]=a.x; v[1]=a.y; v[2]=a.z; v[3]=a.w;
    v[4]=b.x; v[5]=b.y; v[6]=b.z; v[7]=b.w;
}

// ---------------- prep: compose weights, transpose, repack ----------------
__global__ void prep_kernel(const float* __restrict__ W_in, const float* __restrict__ b_in,
                            const float* __restrict__ W_ip, const float* __restrict__ b_ip,
                            const float* __restrict__ conv_w, const float* __restrict__ conv_b,
                            const float* __restrict__ W_op, const float* __restrict__ b_op,
                            const float* __restrict__ W_g2,
                            const float* __restrict__ W_out, const float* __restrict__ b_out,
                            void* __restrict__ ws)
{
    short* w1t  = (short*)((char*)ws + WS_W1T);
    short* w2t  = (short*)((char*)ws + WS_W2T);
    short* wg2t = (short*)((char*)ws + WS_WG2T);
    float* b1   = (float*)((char*)ws + WS_B1);
    float* b2   = (float*)((char*)ws + WS_B2);
    float* cw   = (float*)((char*)ws + WS_CW);   // cw0|cw1|cw2|cb

    int tid = blockIdx.x * blockDim.x + threadIdx.x;
    if (tid < 8192) {                       // W1T[j][c], j<128, c<64
        int j = tid >> 6, c = tid & 63;
        float s = 0.f;
        for (int d = 0; d < 64; ++d) s += W_in[c*64 + d] * W_ip[d*128 + j];
        w1t[j*64 + c] = f2bf(s);
    } else if (tid < 12288) {               // W2T[c'][d]
        int t = tid - 8192; int cp = t >> 6, d = t & 63;
        float s = 0.f;
        for (int e = 0; e < 64; ++e) s += W_op[d*64 + e] * W_out[e*64 + cp];
        w2t[cp*64 + d] = f2bf(s);
    } else if (tid < 13312) {               // Wg2T[c][j]
        int t = tid - 12288; int c = t >> 4, j = t & 15;
        wg2t[c*16 + j] = f2bf(W_g2[j*64 + c]);
    } else if (tid < 13440) {               // b1[j]
        int j = tid - 13312;
        float s = b_ip[j];
        for (int d = 0; d < 64; ++d) s += b_in[d] * W_ip[d*128 + j];
        b1[j] = s;
    } else if (tid < 13504) {               // b2[c']
        int cp = tid - 13440;
        float s = b_out[cp];
        for (int e = 0; e < 64; ++e) s += b_op[e] * W_out[e*64 + cp];
        b2[cp] = s;
    } else if (tid < 13568) {               // conv repack
        int d = tid - 13504;
        cw[d]       = conv_w[3*d + 0];
        cw[64 + d]  = conv_w[3*d + 1];
        cw[128 + d] = conv_w[3*d + 2];
        cw[192 + d] = conv_b[d];
    }
}

// ---------------- fused main kernel ----------------
__global__ __launch_bounds__(256) void fgs_main(
    const float* __restrict__ x, const float* __restrict__ freq,
    const float* __restrict__ wg1, const float* __restrict__ bg1,
    const float* __restrict__ bg2,
    const void* __restrict__ ws, float* __restrict__ out)
{
    const short* w1t  = (const short*)((const char*)ws + WS_W1T);
    const short* w2t  = (const short*)((const char*)ws + WS_W2T);
    const short* wg2t = (const short*)((const char*)ws + WS_WG2T);
    const float* b1   = (const float*)((const char*)ws + WS_B1);
    const float* b2   = (const float*)((const char*)ws + WS_B2);
    const float* cw0p = (const float*)((const char*)ws + WS_CW);
    const float* cw1p = cw0p + 64;
    const float* cw2p = cw0p + 128;
    const float* cbp  = cw0p + 192;

    __shared__ short xb[64][72];   // x-branch (pre-conv), bf16, padded stride
    __shared__ short rs[64][72];   // res branch
    __shared__ short ot[64][72];   // O = silu(conv)*silu(res)
    __shared__ short hl[64][24];   // H = relu(f*Wg1+bg1), 16 cols used

    const int bid   = blockIdx.x;
    const int batch = bid / TILES_PER_B;
    const int tile  = bid % TILES_PER_B;
    const int base  = tile * TILE_OUT;

    const int lane = threadIdx.x & 63;
    const int w    = threadIdx.x >> 6;   // wave 0..3
    const int lr   = lane & 15;          // 16-dim index within frag
    const int g    = lane >> 4;          // k-group 0..3

    const size_t brow0 = (size_t)batch * L_SEQ;

    // ---- GEMM1 (transposed): XR^T[128][64rows] = W1T @ X^T ----
    bf16x8 bx[4][2];                     // x b-frags: [row-tile][kk]
    #pragma unroll
    for (int nt = 0; nt < 4; ++nt) {
        int grow = base - 1 + 16*nt + lr;
        bool v = (grow >= 0) && (grow < L_SEQ);
        const float* xp = x + (brow0 + (size_t)(v ? grow : 0)) * 64;
        #pragma unroll
        for (int kk = 0; kk < 2; ++kk) {
            float vv[8];
            ld8(xp + 32*kk + 8*g, vv);
            bf16x8 f;
            #pragma unroll
            for (int j = 0; j < 8; ++j) f[j] = v ? f2bf(vv[j]) : (short)0;
            bx[nt][kk] = f;
        }
    }

    f32x4 acc1[2][4] = {};               // [p][nt], m-tile = 2w+p
    #pragma unroll
    for (int p = 0; p < 2; ++p) {
        int mt = 2*w + p;
        #pragma unroll
        for (int kk = 0; kk < 2; ++kk) {
            bf16x8 a = *(const bf16x8*)(w1t + (16*mt + lr)*64 + 32*kk + 8*g);
            #pragma unroll
            for (int nt = 0; nt < 4; ++nt)
                acc1[p][nt] = __builtin_amdgcn_mfma_f32_16x16x32_bf16(a, bx[nt][kk], acc1[p][nt], 0, 0, 0);
        }
    }

    // epilogue: +b1, zero out-of-range rows, bf16 -> LDS (waves 0,1: xb; 2,3: res)
    #pragma unroll
    for (int p = 0; p < 2; ++p) {
        int mt = 2*w + p;
        int c0 = 16*mt + 4*g;            // n_out column base (0..127)
        float4 bb = *(const float4*)(b1 + c0);
        #pragma unroll
        for (int nt = 0; nt < 4; ++nt) {
            int trow = 16*nt + lr;
            int grow = base - 1 + trow;
            bool v = (grow >= 0) && (grow < L_SEQ);
            f32x4 a = acc1[p][nt];
            s16x4 pv;
            pv[0] = v ? f2bf(a[0] + bb.x) : (short)0;
            pv[1] = v ? f2bf(a[1] + bb.y) : (short)0;
            pv[2] = v ? f2bf(a[2] + bb.z) : (short)0;
            pv[3] = v ? f2bf(a[3] + bb.w) : (short)0;
            if (mt < 4) *(s16x4*)&xb[trow][c0]      = pv;
            else        *(s16x4*)&rs[trow][c0 - 64] = pv;
        }
    }
    __syncthreads();

    // ---- O phase: conv(k=3) + silu*silu ; H phase: gate hidden ----
    {
        int r = 16*w + lr;               // tile row this lane handles
        int grow = base - 1 + r;
        int cg = grow < 0 ? 0 : (grow >= L_SEQ ? L_SEQ - 1 : grow);
        float f = freq[brow0 + cg];
        if (g < 2) {                     // H[r][8g..8g+7]
            bf16x8 hv;
            #pragma unroll
            for (int j = 0; j < 8; ++j) {
                int jj = 8*g + j;
                hv[j] = f2bf(fmaxf(f * wg1[jj] + bg1[jj], 0.f));
            }
            *(bf16x8*)&hl[r][8*g] = hv;
        }
        #pragma unroll
        for (int kk = 0; kk < 2; ++kk) {
            int d0 = 32*kk + 8*g;
            float w0[8], w1a[8], w2a[8], cbv[8];
            ld8(cw0p + d0, w0); ld8(cw1p + d0, w1a); ld8(cw2p + d0, w2a); ld8(cbp + d0, cbv);
            bf16x8 z = {};
            bf16x8 xm = (r >= 1)  ? *(bf16x8*)&xb[r-1][d0] : z;
            bf16x8 x0 = *(bf16x8*)&xb[r][d0];
            bf16x8 xp = (r <= 62) ? *(bf16x8*)&xb[r+1][d0] : z;
            bf16x8 rr = *(bf16x8*)&rs[r][d0];
            bf16x8 o;
            #pragma unroll
            for (int j = 0; j < 8; ++j) {
                float c = cbv[j] + w0[j]*bf2f(xm[j]) + w1a[j]*bf2f(x0[j]) + w2a[j]*bf2f(xp[j]);
                o[j] = f2bf(fsilu(c) * fsilu(bf2f(rr[j])));
            }
            *(bf16x8*)&ot[r][d0] = o;
        }
    }
    __syncthreads();

    // ---- GEMM2 (transposed): Y^T = W2T @ O^T ; gate GEMM: Wg2T @ H^T ----
    bf16x8 a2_0 = *(const bf16x8*)(w2t + (16*w + lr)*64 + 8*g);
    bf16x8 a2_1 = *(const bf16x8*)(w2t + (16*w + lr)*64 + 32 + 8*g);
    bf16x8 zf = {};
    bf16x8 ag = (g < 2) ? *(const bf16x8*)(wg2t + (16*w + lr)*16 + 8*g) : zf;

    f32x4 acc2[4] = {};
    f32x4 accg[4] = {};
    #pragma unroll
    for (int nt = 0; nt < 4; ++nt) {
        int row = 16*nt + lr;
        bf16x8 bo0 = *(bf16x8*)&ot[row][8*g];
        bf16x8 bo1 = *(bf16x8*)&ot[row][32 + 8*g];
        bf16x8 bh  = (g < 2) ? *(bf16x8*)&hl[row][8*g] : zf;
        acc2[nt] = __builtin_amdgcn_mfma_f32_16x16x32_bf16(a2_0, bo0, acc2[nt], 0, 0, 0);
        acc2[nt] = __builtin_amdgcn_mfma_f32_16x16x32_bf16(a2_1, bo1, acc2[nt], 0, 0, 0);
        accg[nt] = __builtin_amdgcn_mfma_f32_16x16x32_bf16(ag,   bh,  accg[nt], 0, 0, 0);
    }

    // ---- epilogue: y = (Y + b2) * sigmoid(G + bg2), masked float4 stores ----
    {
        int c0 = 16*w + 4*g;
        float4 bb2 = *(const float4*)(b2 + c0);
        float4 bbg = *(const float4*)(bg2 + c0);
        #pragma unroll
        for (int nt = 0; nt < 4; ++nt) {
            int trow = 16*nt + lr;
            int grow = base - 1 + trow;
            if (trow >= 1 && trow <= 62 && grow < L_SEQ) {
                f32x4 y = acc2[nt], gg = accg[nt];
                float4 o;
                o.x = (y[0] + bb2.x) * fsigmoid(gg[0] + bbg.x);
                o.y = (y[1] + bb2.y) * fsigmoid(gg[1] + bbg.y);
                o.z = (y[2] + bb2.z) * fsigmoid(gg[2] + bbg.z);
                o.w = (y[3] + bb2.w) * fsigmoid(gg[3] + bbg.w);
                *(float4*)(out + (brow0 + (size_t)grow) * 64 + c0) = o;
            }
        }
    }
}

extern "C" void kernel_launch(void* const* d_in, const int* in_sizes, int n_in,
                              void* d_out, int out_size, void* d_ws, size_t ws_size,
                              hipStream_t stream)
{
    const float* x      = (const float*)d_in[0];
    const float* freq   = (const float*)d_in[1];
    const float* W_in   = (const float*)d_in[2];
    const float* b_in   = (const float*)d_in[3];
    const float* W_ip   = (const float*)d_in[4];
    const float* b_ip   = (const float*)d_in[5];
    const float* conv_w = (const float*)d_in[6];
    const float* conv_b = (const float*)d_in[7];
    const float* W_op   = (const float*)d_in[8];
    const float* b_op   = (const float*)d_in[9];
    const float* W_g1   = (const float*)d_in[10];
    const float* b_g1   = (const float*)d_in[11];
    const float* W_g2   = (const float*)d_in[12];
    const float* b_g2   = (const float*)d_in[13];
    const float* W_out  = (const float*)d_in[14];
    const float* b_out  = (const float*)d_in[15];
    float* out = (float*)d_out;

    prep_kernel<<<53, 256, 0, stream>>>(W_in, b_in, W_ip, b_ip, conv_w, conv_b,
                                        W_op, b_op, W_g2, W_out, b_out, d_ws);
    fgs_main<<<8 * TILES_PER_B, 256, 0, stream>>>(x, freq, W_g1, b_g1, b_g2, d_ws, out);
}

// Round 2
// 139.607 us; speedup vs baseline: 1.2957x; 1.2957x over previous
//
#include <hip/hip_runtime.h>
#include <hip/hip_bf16.h>

#define L_SEQ 65536
#define TILE_OUT 62
#define TILES_PER_B 1058   // ceil(65536 / 62)

typedef __attribute__((ext_vector_type(8))) short bf16x8;
typedef __attribute__((ext_vector_type(4))) short s16x4;
typedef __attribute__((ext_vector_type(4))) float f32x4;

// workspace layout (bytes)
#define WS_W1T   0        // bf16 [128][64]  : W1T[j][c] = (W_in@W_ip)^T
#define WS_W2T   16384    // bf16 [64][64]   : W2T[c'][d] = (W_op@W_out)^T
#define WS_WG2T  24576    // bf16 [64][16]   : Wg2T[c][j] = W_g2[j][c]
#define WS_B1    26624    // f32 [128]
#define WS_B2    27136    // f32 [64]
#define WS_CW    27392    // f32 cw0[64] cw1[64] cw2[64] cb[64]

__device__ __forceinline__ short f2bf(float f) {
    __bf16 h = (__bf16)f;                     // native v_cvt (pairs pack to v_cvt_pk_bf16_f32)
    return __builtin_bit_cast(short, h);
}
__device__ __forceinline__ float bf2f(short s) {
    return (float)__builtin_bit_cast(__bf16, s);
}
__device__ __forceinline__ float fsigmoid(float x) {
    // 1 v_mul + 1 v_exp + 1 v_add + 1 v_rcp  (vs full-precision div: ~15 ops)
    return __builtin_amdgcn_rcpf(1.0f + __builtin_amdgcn_exp2f(-1.44269504089f * x));
}
__device__ __forceinline__ float fsilu(float x) { return x * fsigmoid(x); }

__device__ __forceinline__ void ld8(const float* __restrict__ p, float* v) {
    float4 a = *(const float4*)p;
    float4 b = *(const float4*)(p + 4);
    v[0]=a.x; v[1]=a.y; v[2]=a.z; v[3]=a.w;
    v[4]=b.x; v[5]=b.y; v[6]=b.z; v[7]=b.w;
}

// ---------------- prep: compose weights, transpose, repack ----------------
__global__ void prep_kernel(const float* __restrict__ W_in, const float* __restrict__ b_in,
                            const float* __restrict__ W_ip, const float* __restrict__ b_ip,
                            const float* __restrict__ conv_w, const float* __restrict__ conv_b,
                            const float* __restrict__ W_op, const float* __restrict__ b_op,
                            const float* __restrict__ W_g2,
                            const float* __restrict__ W_out, const float* __restrict__ b_out,
                            void* __restrict__ ws)
{
    short* w1t  = (short*)((char*)ws + WS_W1T);
    short* w2t  = (short*)((char*)ws + WS_W2T);
    short* wg2t = (short*)((char*)ws + WS_WG2T);
    float* b1   = (float*)((char*)ws + WS_B1);
    float* b2   = (float*)((char*)ws + WS_B2);
    float* cw   = (float*)((char*)ws + WS_CW);   // cw0|cw1|cw2|cb

    int tid = blockIdx.x * blockDim.x + threadIdx.x;
    if (tid < 8192) {                       // W1T[j][c], j<128, c<64
        int j = tid >> 6, c = tid & 63;
        float s = 0.f;
        for (int d = 0; d < 64; ++d) s += W_in[c*64 + d] * W_ip[d*128 + j];
        w1t[j*64 + c] = f2bf(s);
    } else if (tid < 12288) {               // W2T[c'][d]
        int t = tid - 8192; int cp = t >> 6, d = t & 63;
        float s = 0.f;
        for (int e = 0; e < 64; ++e) s += W_op[d*64 + e] * W_out[e*64 + cp];
        w2t[cp*64 + d] = f2bf(s);
    } else if (tid < 13312) {               // Wg2T[c][j]
        int t = tid - 12288; int c = t >> 4, j = t & 15;
        wg2t[c*16 + j] = f2bf(W_g2[j*64 + c]);
    } else if (tid < 13440) {               // b1[j]
        int j = tid - 13312;
        float s = b_ip[j];
        for (int d = 0; d < 64; ++d) s += b_in[d] * W_ip[d*128 + j];
        b1[j] = s;
    } else if (tid < 13504) {               // b2[c']
        int cp = tid - 13440;
        float s = b_out[cp];
        for (int e = 0; e < 64; ++e) s += b_op[e] * W_out[e*64 + cp];
        b2[cp] = s;
    } else if (tid < 13568) {               // conv repack
        int d = tid - 13504;
        cw[d]       = conv_w[3*d + 0];
        cw[64 + d]  = conv_w[3*d + 1];
        cw[128 + d] = conv_w[3*d + 2];
        cw[192 + d] = conv_b[d];
    }
}

// ---------------- fused main kernel ----------------
// LDS = 9216 + 9216 + 2048 = 20480 B -> 8 blocks/CU (160 KiB exactly)
__global__ __launch_bounds__(256) void fgs_main(
    const float* __restrict__ x, const float* __restrict__ freq,
    const float* __restrict__ wg1, const float* __restrict__ bg1,
    const float* __restrict__ bg2,
    const void* __restrict__ ws, float* __restrict__ out)
{
    const short* w1t  = (const short*)((const char*)ws + WS_W1T);
    const short* w2t  = (const short*)((const char*)ws + WS_W2T);
    const short* wg2t = (const short*)((const char*)ws + WS_WG2T);
    const float* b1   = (const float*)((const char*)ws + WS_B1);
    const float* b2   = (const float*)((const char*)ws + WS_B2);
    const float* cw0p = (const float*)((const char*)ws + WS_CW);
    const float* cw1p = cw0p + 64;
    const float* cw2p = cw0p + 128;
    const float* cbp  = cw0p + 192;

    __shared__ short xb[64][72];   // x-branch (pre-conv), bf16, padded stride
    __shared__ short rs[64][72];   // res branch; conv output O written in-place
    __shared__ short hl[64][16];   // H = relu(f*Wg1+bg1)

    const int bid   = blockIdx.x;
    const int batch = bid / TILES_PER_B;
    const int tile  = bid % TILES_PER_B;
    const int base  = tile * TILE_OUT;
    const bool edge = (tile == 0) || (base + TILE_OUT >= L_SEQ);

    const int lane = threadIdx.x & 63;
    const int w    = threadIdx.x >> 6;   // wave 0..3
    const int lr   = lane & 15;          // 16-dim index within frag
    const int g    = lane >> 4;          // k-group 0..3

    const size_t brow0 = (size_t)batch * L_SEQ;

    // ---- GEMM1 (transposed): XR^T[128][64rows] = W1T @ X^T ----
    bf16x8 bx[4][2];                     // x b-frags: [row-tile][kk]
    if (!edge) {
        #pragma unroll
        for (int nt = 0; nt < 4; ++nt) {
            const float* xp = x + (brow0 + (size_t)(base - 1 + 16*nt + lr)) * 64;
            #pragma unroll
            for (int kk = 0; kk < 2; ++kk) {
                float vv[8];
                ld8(xp + 32*kk + 8*g, vv);
                bf16x8 f;
                #pragma unroll
                for (int j = 0; j < 8; ++j) f[j] = f2bf(vv[j]);
                bx[nt][kk] = f;
            }
        }
    } else {
        #pragma unroll
        for (int nt = 0; nt < 4; ++nt) {
            int grow = base - 1 + 16*nt + lr;
            bool v = (grow >= 0) && (grow < L_SEQ);
            const float* xp = x + (brow0 + (size_t)(v ? grow : 0)) * 64;
            #pragma unroll
            for (int kk = 0; kk < 2; ++kk) {
                float vv[8];
                ld8(xp + 32*kk + 8*g, vv);
                bf16x8 f;
                #pragma unroll
                for (int j = 0; j < 8; ++j) f[j] = v ? f2bf(vv[j]) : (short)0;
                bx[nt][kk] = f;
            }
        }
    }

    f32x4 acc1[2][4] = {};               // [p][nt], m-tile = 2w+p
    #pragma unroll
    for (int p = 0; p < 2; ++p) {
        int mt = 2*w + p;
        #pragma unroll
        for (int kk = 0; kk < 2; ++kk) {
            bf16x8 a = *(const bf16x8*)(w1t + (16*mt + lr)*64 + 32*kk + 8*g);
            #pragma unroll
            for (int nt = 0; nt < 4; ++nt)
                acc1[p][nt] = __builtin_amdgcn_mfma_f32_16x16x32_bf16(a, bx[nt][kk], acc1[p][nt], 0, 0, 0);
        }
    }

    // epilogue: +b1, bf16 -> LDS (waves 0,1: xb; 2,3: rs); zero OOB rows on edge tiles
    #pragma unroll
    for (int p = 0; p < 2; ++p) {
        int mt = 2*w + p;
        int c0 = 16*mt + 4*g;            // n_out column base (0..127)
        float4 bb = *(const float4*)(b1 + c0);
        short* dst = (mt < 4) ? &xb[0][c0] : &rs[0][c0 - 64];
        #pragma unroll
        for (int nt = 0; nt < 4; ++nt) {
            int trow = 16*nt + lr;
            f32x4 a = acc1[p][nt];
            s16x4 pv;
            pv[0] = f2bf(a[0] + bb.x);
            pv[1] = f2bf(a[1] + bb.y);
            pv[2] = f2bf(a[2] + bb.z);
            pv[3] = f2bf(a[3] + bb.w);
            if (edge) {
                int grow = base - 1 + trow;
                if (grow < 0 || grow >= L_SEQ) { pv[0]=0; pv[1]=0; pv[2]=0; pv[3]=0; }
            }
            *(s16x4*)(dst + trow*72) = pv;
        }
    }
    __syncthreads();

    // ---- O phase: conv(k=3) + silu*silu (in-place into rs) ; H phase: gate hidden ----
    {
        int r = 16*w + lr;               // tile row this lane handles
        int grow = base - 1 + r;
        int cg = grow < 0 ? 0 : (grow >= L_SEQ ? L_SEQ - 1 : grow);
        float f = freq[brow0 + cg];
        if (g < 2) {                     // H[r][8g..8g+7]
            bf16x8 hv;
            #pragma unroll
            for (int j = 0; j < 8; ++j) {
                int jj = 8*g + j;
                hv[j] = f2bf(fmaxf(f * wg1[jj] + bg1[jj], 0.f));
            }
            *(bf16x8*)&hl[r][8*g] = hv;
        }
        int rm = (r >= 1)  ? r - 1 : 0;  // rows 0/63 produce garbage; outputs masked at store
        int rp = (r <= 62) ? r + 1 : 63;
        #pragma unroll
        for (int kk = 0; kk < 2; ++kk) {
            int d0 = 32*kk + 8*g;
            float w0[8], w1a[8], w2a[8], cbv[8];
            ld8(cw0p + d0, w0); ld8(cw1p + d0, w1a); ld8(cw2p + d0, w2a); ld8(cbp + d0, cbv);
            bf16x8 xm = *(bf16x8*)&xb[rm][d0];
            bf16x8 x0 = *(bf16x8*)&xb[r][d0];
            bf16x8 xp = *(bf16x8*)&xb[rp][d0];
            bf16x8 rr = *(bf16x8*)&rs[r][d0];
            bf16x8 o;
            #pragma unroll
            for (int j = 0; j < 8; ++j) {
                float c = cbv[j] + w0[j]*bf2f(xm[j]) + w1a[j]*bf2f(x0[j]) + w2a[j]*bf2f(xp[j]);
                o[j] = f2bf(fsilu(c) * fsilu(bf2f(rr[j])));
            }
            *(bf16x8*)&rs[r][d0] = o;    // in-place: same lane read these slots above
        }
    }
    __syncthreads();

    // ---- GEMM2 (transposed): Y^T = W2T @ O^T ; gate GEMM: Wg2T @ H^T ----
    bf16x8 a2_0 = *(const bf16x8*)(w2t + (16*w + lr)*64 + 8*g);
    bf16x8 a2_1 = *(const bf16x8*)(w2t + (16*w + lr)*64 + 32 + 8*g);
    bf16x8 zf = {};
    bf16x8 ag = (g < 2) ? *(const bf16x8*)(wg2t + (16*w + lr)*16 + 8*g) : zf;

    f32x4 acc2[4] = {};
    f32x4 accg[4] = {};
    #pragma unroll
    for (int nt = 0; nt < 4; ++nt) {
        int row = 16*nt + lr;
        bf16x8 bo0 = *(bf16x8*)&rs[row][8*g];
        bf16x8 bo1 = *(bf16x8*)&rs[row][32 + 8*g];
        bf16x8 bh  = (g < 2) ? *(bf16x8*)&hl[row][8*g] : zf;
        acc2[nt] = __builtin_amdgcn_mfma_f32_16x16x32_bf16(a2_0, bo0, acc2[nt], 0, 0, 0);
        acc2[nt] = __builtin_amdgcn_mfma_f32_16x16x32_bf16(a2_1, bo1, acc2[nt], 0, 0, 0);
        accg[nt] = __builtin_amdgcn_mfma_f32_16x16x32_bf16(ag,   bh,  accg[nt], 0, 0, 0);
    }

    // ---- epilogue: y = (Y + b2) * sigmoid(G + bg2), masked float4 stores ----
    {
        int c0 = 16*w + 4*g;
        float4 bb2 = *(const float4*)(b2 + c0);
        float4 bbg = *(const float4*)(bg2 + c0);
        #pragma unroll
        for (int nt = 0; nt < 4; ++nt) {
            int trow = 16*nt + lr;
            int grow = base - 1 + trow;
            if (trow >= 1 && trow <= 62 && grow < L_SEQ) {
                f32x4 y = acc2[nt], gg = accg[nt];
                float4 o;
                o.x = (y[0] + bb2.x) * fsigmoid(gg[0] + bbg.x);
                o.y = (y[1] + bb2.y) * fsigmoid(gg[1] + bbg.y);
                o.z = (y[2] + bb2.z) * fsigmoid(gg[2] + bbg.z);
                o.w = (y[3] + bb2.w) * fsigmoid(gg[3] + bbg.w);
                *(float4*)(out + (brow0 + (size_t)grow) * 64 + c0) = o;
            }
        }
    }
}

extern "C" void kernel_launch(void* const* d_in, const int* in_sizes, int n_in,
                              void* d_out, int out_size, void* d_ws, size_t ws_size,
                              hipStream_t stream)
{
    const float* x      = (const float*)d_in[0];
    const float* freq   = (const float*)d_in[1];
    const float* W_in   = (const float*)d_in[2];
    const float* b_in   = (const float*)d_in[3];
    const float* W_ip   = (const float*)d_in[4];
    const float* b_ip   = (const float*)d_in[5];
    const float* conv_w = (const float*)d_in[6];
    const float* conv_b = (const float*)d_in[7];
    const float* W_op   = (const float*)d_in[8];
    const float* b_op   = (const float*)d_in[9];
    const float* W_g1   = (const float*)d_in[10];
    const float* b_g1   = (const float*)d_in[11];
    const float* W_g2   = (const float*)d_in[12];
    const float* b_g2   = (const float*)d_in[13];
    const float* W_out  = (const float*)d_in[14];
    const float* b_out  = (const float*)d_in[15];
    float* out = (float*)d_out;

    prep_kernel<<<53, 256, 0, stream>>>(W_in, b_in, W_ip, b_ip, conv_w, conv_b,
                                        W_op, b_op, W_g2, W_out, b_out, d_ws);
    fgs_main<<<8 * TILES_PER_B, 256, 0, stream>>>(x, freq, W_g1, b_g1, b_g2, d_ws, out);
}

// Round 3
// 125.343 us; speedup vs baseline: 1.4431x; 1.1138x over previous
//
#include <hip/hip_runtime.h>
#include <hip/hip_bf16.h>

#define L_SEQ 65536
#define TILE_OUT 62
#define TILES_PER_B 1058   // ceil(65536 / 62)

typedef __attribute__((ext_vector_type(8))) short bf16x8;
typedef __attribute__((ext_vector_type(4))) short s16x4;
typedef __attribute__((ext_vector_type(4))) float f32x4;

// workspace layout (bytes)
#define WS_W1T   0        // bf16 [128][64]  : W1T[j][c] = (W_in@W_ip)^T
#define WS_W2T   16384    // bf16 [64][64]   : W2T[c'][d] = (W_op@W_out)^T
#define WS_WG2T  24576    // bf16 [64][16]   : Wg2T[c][j] = W_g2[j][c]
#define WS_B1    26624    // f32 [128]
#define WS_B2    27136    // f32 [64]
#define WS_CW    27392    // f32 cw0[64] cw1[64] cw2[64] cb[64]  (256 floats contiguous)

__device__ __forceinline__ short f2bf(float f) {
    __bf16 h = (__bf16)f;                     // native cvt; pairs pack to v_cvt_pk_bf16_f32
    return __builtin_bit_cast(short, h);
}
__device__ __forceinline__ float bf2f(short s) {
    return (float)__builtin_bit_cast(__bf16, s);
}
__device__ __forceinline__ float fsigmoid(float x) {
    return __builtin_amdgcn_rcpf(1.0f + __builtin_amdgcn_exp2f(-1.44269504089f * x));
}
__device__ __forceinline__ float fsilu(float x) { return x * fsigmoid(x); }

__device__ __forceinline__ void ld8(const float* __restrict__ p, float* v) {
    float4 a = *(const float4*)p;
    float4 b = *(const float4*)(p + 4);
    v[0]=a.x; v[1]=a.y; v[2]=a.z; v[3]=a.w;
    v[4]=b.x; v[5]=b.y; v[6]=b.z; v[7]=b.w;
}

// ---------------- prep: compose weights, transpose, repack ----------------
__global__ void prep_kernel(const float* __restrict__ W_in, const float* __restrict__ b_in,
                            const float* __restrict__ W_ip, const float* __restrict__ b_ip,
                            const float* __restrict__ conv_w, const float* __restrict__ conv_b,
                            const float* __restrict__ W_op, const float* __restrict__ b_op,
                            const float* __restrict__ W_g2,
                            const float* __restrict__ W_out, const float* __restrict__ b_out,
                            void* __restrict__ ws)
{
    short* w1t  = (short*)((char*)ws + WS_W1T);
    short* w2t  = (short*)((char*)ws + WS_W2T);
    short* wg2t = (short*)((char*)ws + WS_WG2T);
    float* b1   = (float*)((char*)ws + WS_B1);
    float* b2   = (float*)((char*)ws + WS_B2);
    float* cw   = (float*)((char*)ws + WS_CW);   // cw0|cw1|cw2|cb

    int tid = blockIdx.x * blockDim.x + threadIdx.x;
    if (tid < 8192) {                       // W1T[j][c], j<128, c<64
        int j = tid >> 6, c = tid & 63;
        float s = 0.f;
        for (int d = 0; d < 64; ++d) s += W_in[c*64 + d] * W_ip[d*128 + j];
        w1t[j*64 + c] = f2bf(s);
    } else if (tid < 12288) {               // W2T[c'][d]
        int t = tid - 8192; int cp = t >> 6, d = t & 63;
        float s = 0.f;
        for (int e = 0; e < 64; ++e) s += W_op[d*64 + e] * W_out[e*64 + cp];
        w2t[cp*64 + d] = f2bf(s);
    } else if (tid < 13312) {               // Wg2T[c][j]
        int t = tid - 12288; int c = t >> 4, j = t & 15;
        wg2t[c*16 + j] = f2bf(W_g2[j*64 + c]);
    } else if (tid < 13440) {               // b1[j]
        int j = tid - 13312;
        float s = b_ip[j];
        for (int d = 0; d < 64; ++d) s += b_in[d] * W_ip[d*128 + j];
        b1[j] = s;
    } else if (tid < 13504) {               // b2[c']
        int cp = tid - 13440;
        float s = b_out[cp];
        for (int e = 0; e < 64; ++e) s += b_op[e] * W_out[e*64 + cp];
        b2[cp] = s;
    } else if (tid < 13568) {               // conv repack
        int d = tid - 13504;
        cw[d]       = conv_w[3*d + 0];
        cw[64 + d]  = conv_w[3*d + 1];
        cw[128 + d] = conv_w[3*d + 2];
        cw[192 + d] = conv_b[d];
    }
}

// ---------------- fused main kernel ----------------
// LDS = 9216 + 9216 + 2048 + 1024 = 21504 B -> 7 blocks/CU
// __launch_bounds__(256,8): force VGPR<=64 -> 8 waves/SIMD cap
__global__ __launch_bounds__(256, 8) void fgs_main(
    const float* __restrict__ x, const float* __restrict__ freq,
    const float* __restrict__ wg1, const float* __restrict__ bg1,
    const float* __restrict__ bg2,
    const void* __restrict__ ws, float* __restrict__ out)
{
    const short* w1t  = (const short*)((const char*)ws + WS_W1T);
    const short* w2t  = (const short*)((const char*)ws + WS_W2T);
    const short* wg2t = (const short*)((const char*)ws + WS_WG2T);
    const float* b1   = (const float*)((const char*)ws + WS_B1);
    const float* b2   = (const float*)((const char*)ws + WS_B2);
    const float* cwg  = (const float*)((const char*)ws + WS_CW);   // 256 floats

    __shared__ short xb[64][72];   // x-branch (pre-conv), bf16, padded stride
    __shared__ short rs[64][72];   // res branch; conv output O written in-place
    __shared__ short hl[64][16];   // H = relu(f*Wg1+bg1)
    __shared__ float cwl[4][64];   // conv w0|w1|w2|cb staged in LDS

    const int bid   = blockIdx.x;
    const int batch = bid / TILES_PER_B;
    const int tile  = bid % TILES_PER_B;
    const int base  = tile * TILE_OUT;
    const bool edge = (tile == 0) || (base + TILE_OUT >= L_SEQ);

    const int lane = threadIdx.x & 63;
    const int w    = threadIdx.x >> 6;   // wave 0..3
    const int lr   = lane & 15;          // 16-dim index within frag
    const int g    = lane >> 4;          // k-group 0..3
    const int r    = 16*w + lr;          // this lane's tile row (conv/hl phases)

    const size_t brow0 = (size_t)batch * L_SEQ;

    // ---- stage conv weights to LDS (1 float/thread, coalesced) ----
    ((float*)cwl)[threadIdx.x] = cwg[threadIdx.x];

    // ---- gate hidden H (hoisted above barrier 1; hides under GEMM1) ----
    if (g < 2) {
        int growf = base - 1 + r;
        int cg = growf < 0 ? 0 : (growf >= L_SEQ ? L_SEQ - 1 : growf);
        float f = freq[brow0 + cg];
        float wv[8], bv[8];
        ld8(wg1 + 8*g, wv); ld8(bg1 + 8*g, bv);
        bf16x8 hv;
        #pragma unroll
        for (int j = 0; j < 8; ++j) hv[j] = f2bf(fmaxf(f * wv[j] + bv[j], 0.f));
        *(bf16x8*)&hl[r][8*g] = hv;
    }

    // ---- GEMM1 (transposed, K-split): XR^T[128][64rows] = W1T @ X^T ----
    f32x4 acc1[2][4] = {};               // [p][nt], m-tile = 2w+p
    #pragma unroll
    for (int kk = 0; kk < 2; ++kk) {
        bf16x8 bx[4];
        if (!edge) {
            #pragma unroll
            for (int nt = 0; nt < 4; ++nt) {
                const float* xp = x + (brow0 + (size_t)(base - 1 + 16*nt + lr)) * 64 + 32*kk + 8*g;
                float vv[8];
                ld8(xp, vv);
                bf16x8 f;
                #pragma unroll
                for (int j = 0; j < 8; ++j) f[j] = f2bf(vv[j]);
                bx[nt] = f;
            }
        } else {
            #pragma unroll
            for (int nt = 0; nt < 4; ++nt) {
                int grow = base - 1 + 16*nt + lr;
                bool v = (grow >= 0) && (grow < L_SEQ);
                const float* xp = x + (brow0 + (size_t)(v ? grow : 0)) * 64 + 32*kk + 8*g;
                float vv[8];
                ld8(xp, vv);
                bf16x8 f;
                #pragma unroll
                for (int j = 0; j < 8; ++j) f[j] = v ? f2bf(vv[j]) : (short)0;
                bx[nt] = f;
            }
        }
        #pragma unroll
        for (int p = 0; p < 2; ++p) {
            bf16x8 a = *(const bf16x8*)(w1t + (16*(2*w + p) + lr)*64 + 32*kk + 8*g);
            #pragma unroll
            for (int nt = 0; nt < 4; ++nt)
                acc1[p][nt] = __builtin_amdgcn_mfma_f32_16x16x32_bf16(a, bx[nt], acc1[p][nt], 0, 0, 0);
        }
    }

    // epilogue: +b1, bf16 -> LDS (m-tiles 0..3: xb; 4..7: rs); zero OOB rows on edge tiles
    #pragma unroll
    for (int p = 0; p < 2; ++p) {
        int mt = 2*w + p;
        int c0 = 16*mt + 4*g;            // n_out column base (0..127)
        float4 bb = *(const float4*)(b1 + c0);
        short* dst = (mt < 4) ? &xb[0][c0] : &rs[0][c0 - 64];
        #pragma unroll
        for (int nt = 0; nt < 4; ++nt) {
            int trow = 16*nt + lr;
            f32x4 a = acc1[p][nt];
            s16x4 pv;
            pv[0] = f2bf(a[0] + bb.x);
            pv[1] = f2bf(a[1] + bb.y);
            pv[2] = f2bf(a[2] + bb.z);
            pv[3] = f2bf(a[3] + bb.w);
            if (edge) {
                int grow = base - 1 + trow;
                if (grow < 0 || grow >= L_SEQ) { pv[0]=0; pv[1]=0; pv[2]=0; pv[3]=0; }
            }
            *(s16x4*)(dst + trow*72) = pv;
        }
    }
    __syncthreads();

    // ---- O phase: conv(k=3) + silu*silu (in-place into rs) ----
    {
        int rm = (r >= 1)  ? r - 1 : 0;  // rows 0/63 produce garbage; masked at store
        int rp = (r <= 62) ? r + 1 : 63;
        #pragma unroll
        for (int kk = 0; kk < 2; ++kk) {
            int d0 = 32*kk + 8*g;
            float w0[8], w1a[8], w2a[8], cbv[8];
            ld8(&cwl[0][d0], w0); ld8(&cwl[1][d0], w1a);
            ld8(&cwl[2][d0], w2a); ld8(&cwl[3][d0], cbv);
            bf16x8 xm = *(bf16x8*)&xb[rm][d0];
            bf16x8 x0 = *(bf16x8*)&xb[r][d0];
            bf16x8 xp = *(bf16x8*)&xb[rp][d0];
            bf16x8 rr = *(bf16x8*)&rs[r][d0];
            bf16x8 o;
            #pragma unroll
            for (int j = 0; j < 8; ++j) {
                float c = cbv[j] + w0[j]*bf2f(xm[j]) + w1a[j]*bf2f(x0[j]) + w2a[j]*bf2f(xp[j]);
                o[j] = f2bf(fsilu(c) * fsilu(bf2f(rr[j])));
            }
            *(bf16x8*)&rs[r][d0] = o;    // in-place: same lane read these slots above
        }
    }
    __syncthreads();

    // ---- GEMM2 (transposed): Y^T = W2T @ O^T ; then gate GEMM: Wg2T @ H^T ----
    f32x4 acc2[4] = {};
    {
        bf16x8 a2_0 = *(const bf16x8*)(w2t + (16*w + lr)*64 + 8*g);
        bf16x8 a2_1 = *(const bf16x8*)(w2t + (16*w + lr)*64 + 32 + 8*g);
        #pragma unroll
        for (int nt = 0; nt < 4; ++nt) {
            int row = 16*nt + lr;
            bf16x8 bo0 = *(bf16x8*)&rs[row][8*g];
            bf16x8 bo1 = *(bf16x8*)&rs[row][32 + 8*g];
            acc2[nt] = __builtin_amdgcn_mfma_f32_16x16x32_bf16(a2_0, bo0, acc2[nt], 0, 0, 0);
            acc2[nt] = __builtin_amdgcn_mfma_f32_16x16x32_bf16(a2_1, bo1, acc2[nt], 0, 0, 0);
        }
    }
    f32x4 accg[4] = {};
    {
        bf16x8 zf = {};
        bf16x8 ag = (g < 2) ? *(const bf16x8*)(wg2t + (16*w + lr)*16 + 8*g) : zf;
        #pragma unroll
        for (int nt = 0; nt < 4; ++nt) {
            int row = 16*nt + lr;
            bf16x8 bh = (g < 2) ? *(bf16x8*)&hl[row][8*g] : zf;
            accg[nt] = __builtin_amdgcn_mfma_f32_16x16x32_bf16(ag, bh, accg[nt], 0, 0, 0);
        }
    }

    // ---- epilogue: y = (Y + b2) * sigmoid(G + bg2), masked float4 stores ----
    {
        int c0 = 16*w + 4*g;
        float4 bb2 = *(const float4*)(b2 + c0);
        float4 bbg = *(const float4*)(bg2 + c0);
        #pragma unroll
        for (int nt = 0; nt < 4; ++nt) {
            int trow = 16*nt + lr;
            int grow = base - 1 + trow;
            if (trow >= 1 && trow <= 62 && grow < L_SEQ) {
                f32x4 y = acc2[nt], gg = accg[nt];
                float4 o;
                o.x = (y[0] + bb2.x) * fsigmoid(gg[0] + bbg.x);
                o.y = (y[1] + bb2.y) * fsigmoid(gg[1] + bbg.y);
                o.z = (y[2] + bb2.z) * fsigmoid(gg[2] + bbg.z);
                o.w = (y[3] + bb2.w) * fsigmoid(gg[3] + bbg.w);
                *(float4*)(out + (brow0 + (size_t)grow) * 64 + c0) = o;
            }
        }
    }
}

extern "C" void kernel_launch(void* const* d_in, const int* in_sizes, int n_in,
                              void* d_out, int out_size, void* d_ws, size_t ws_size,
                              hipStream_t stream)
{
    const float* x      = (const float*)d_in[0];
    const float* freq   = (const float*)d_in[1];
    const float* W_in   = (const float*)d_in[2];
    const float* b_in   = (const float*)d_in[3];
    const float* W_ip   = (const float*)d_in[4];
    const float* b_ip   = (const float*)d_in[5];
    const float* conv_w = (const float*)d_in[6];
    const float* conv_b = (const float*)d_in[7];
    const float* W_op   = (const float*)d_in[8];
    const float* b_op   = (const float*)d_in[9];
    const float* W_g1   = (const float*)d_in[10];
    const float* b_g1   = (const float*)d_in[11];
    const float* W_g2   = (const float*)d_in[12];
    const float* b_g2   = (const float*)d_in[13];
    const float* W_out  = (const float*)d_in[14];
    const float* b_out  = (const float*)d_in[15];
    float* out = (float*)d_out;

    prep_kernel<<<53, 256, 0, stream>>>(W_in, b_in, W_ip, b_ip, conv_w, conv_b,
                                        W_op, b_op, W_g2, W_out, b_out, d_ws);
    fgs_main<<<8 * TILES_PER_B, 256, 0, stream>>>(x, freq, W_g1, b_g1, b_g2, d_ws, out);
}